// Round 1
// baseline (542.208 us; speedup 1.0000x reference)
//
#include <hip/hip_runtime.h>
#include <hip/hip_bf16.h>

#define NNODES 131072
#define NEDGES 2097152
#define BSUB   1024
#define SSUB   128
#define FIN    300
#define FOUT   64

typedef __attribute__((ext_vector_type(8))) short short8;
typedef __attribute__((ext_vector_type(4))) float f32x4;

__device__ inline short f2bf(float f) {
    unsigned u = __float_as_uint(f);
    u = (u + 0x7FFFu + ((u >> 16) & 1u)) >> 16;   // round-to-nearest-even
    return (short)u;
}

// ---------------------------------------------------------------------------
// Pack W [300][64] f32 into MFMA B-fragment layout, zero-padded to K=320.
// wfrag[((ct*10 + kt)*64 + lane)*8 + e] = bf16(W[kt*32 + (lane>>4)*8 + e][ct*16 + (lane&15)])
// ---------------------------------------------------------------------------
__global__ __launch_bounds__(256) void prep_w_kernel(const float* __restrict__ W,
                                                     short* __restrict__ wfrag) {
    int idx = blockIdx.x * 256 + threadIdx.x;     // 0..2559
    if (idx >= 2560) return;
    int ct   = idx / 640;
    int rem  = idx % 640;
    int kt   = rem / 64;
    int lane = rem % 64;
    int col  = ct * 16 + (lane & 15);
    int kb   = kt * 32 + (lane >> 4) * 8;
#pragma unroll
    for (int e = 0; e < 8; ++e) {
        int k = kb + e;
        float v = (k < FIN) ? W[(size_t)k * FOUT + col] : 0.f;
        wfrag[(size_t)idx * 8 + e] = f2bf(v);
    }
}

// ---------------------------------------------------------------------------
// Degree counting
// ---------------------------------------------------------------------------
__global__ __launch_bounds__(256) void count_deg_kernel(const int* __restrict__ src,
                                                        const int* __restrict__ dst,
                                                        int* __restrict__ deg_out,
                                                        int* __restrict__ deg_in) {
    int e = blockIdx.x * 256 + threadIdx.x;
    atomicAdd(&deg_out[src[e]], 1);
    atomicAdd(&deg_in[dst[e]], 1);
}

// ---------------------------------------------------------------------------
// Assign contiguous CSR ranges per dst node (order-free: one global cursor,
// one atomic per wave, wave-prefix-scan within).
// ---------------------------------------------------------------------------
__global__ __launch_bounds__(256) void assign_off_kernel(const int* __restrict__ deg_in,
                                                         int* __restrict__ offs,
                                                         int* __restrict__ cursor,
                                                         int* __restrict__ gcount) {
    int n = blockIdx.x * 256 + threadIdx.x;
    int lane = threadIdx.x & 63;
    int d = deg_in[n];
    int pre = d;
#pragma unroll
    for (int o = 1; o < 64; o <<= 1) {
        int t = __shfl_up(pre, o, 64);
        if (lane >= o) pre += t;
    }
    int total = __shfl(pre, 63, 64);
    int base = 0;
    if (lane == 63) base = atomicAdd(gcount, total);
    base = __shfl(base, 63, 64);
    int my = base + pre - d;
    offs[n] = my;
    cursor[n] = my;
}

// ---------------------------------------------------------------------------
// Bucket edges into CSR slots (by dst, storing src)
// ---------------------------------------------------------------------------
__global__ __launch_bounds__(256) void bucket_kernel(const int* __restrict__ src,
                                                     const int* __restrict__ dst,
                                                     int* __restrict__ cursor,
                                                     int* __restrict__ ssrc) {
    int e = blockIdx.x * 256 + threadIdx.x;
    int d = dst[e];
    int p = atomicAdd(&cursor[d], 1);
    ssrc[p] = src[e];
}

// ---------------------------------------------------------------------------
// h = (in_feat * rsqrt(deg_out)) @ W    via bf16 MFMA 16x16x32
// One wave per 16 rows; A-frags loaded straight from global f32, scaled,
// converted to bf16 in registers. 4 col-tiles (FOUT=64). K padded to 320.
// ---------------------------------------------------------------------------
__global__ __launch_bounds__(256) void gemm_kernel(const float* __restrict__ x,
                                                   const int* __restrict__ deg_out,
                                                   const short* __restrict__ wfrag,
                                                   float* __restrict__ h) {
    const int wave = threadIdx.x >> 6;
    const int lane = threadIdx.x & 63;
    const int rowbase = (blockIdx.x * 4 + wave) * 16;
    const int arow = rowbase + (lane & 15);
    const int kgrp = lane >> 4;
    const float rs = rsqrtf((float)max(deg_out[arow], 1));

    f32x4 acc[4];
#pragma unroll
    for (int c = 0; c < 4; ++c) acc[c] = (f32x4){0.f, 0.f, 0.f, 0.f};

    const float* ap = x + (size_t)arow * FIN + kgrp * 8;
#pragma unroll
    for (int kt = 0; kt < 9; ++kt) {
        f32x4 lo = *(const f32x4*)(ap + kt * 32);
        f32x4 hi = *(const f32x4*)(ap + kt * 32 + 4);
        short8 afr;
        afr[0] = f2bf(lo[0] * rs); afr[1] = f2bf(lo[1] * rs);
        afr[2] = f2bf(lo[2] * rs); afr[3] = f2bf(lo[3] * rs);
        afr[4] = f2bf(hi[0] * rs); afr[5] = f2bf(hi[1] * rs);
        afr[6] = f2bf(hi[2] * rs); afr[7] = f2bf(hi[3] * rs);
#pragma unroll
        for (int ct = 0; ct < 4; ++ct) {
            short8 bfr = *(const short8*)(wfrag + ((size_t)(ct * 10 + kt) * 64 + lane) * 8);
            acc[ct] = __builtin_amdgcn_mfma_f32_16x16x32_bf16(afr, bfr, acc[ct], 0, 0, 0);
        }
    }
    {   // K tail: kt = 9 covers k 288..319, valid only k<300 (predicated scalar loads)
        short8 afr;
#pragma unroll
        for (int e = 0; e < 8; ++e) {
            int k = 288 + kgrp * 8 + e;
            float v = (k < FIN) ? x[(size_t)arow * FIN + k] * rs : 0.f;
            afr[e] = f2bf(v);
        }
#pragma unroll
        for (int ct = 0; ct < 4; ++ct) {
            short8 bfr = *(const short8*)(wfrag + ((size_t)(ct * 10 + 9) * 64 + lane) * 8);
            acc[ct] = __builtin_amdgcn_mfma_f32_16x16x32_bf16(afr, bfr, acc[ct], 0, 0, 0);
        }
    }
    // D layout: row = (lane>>4)*4 + r, col = ct*16 + (lane&15)
    const int orow = rowbase + (lane >> 4) * 4;
    const int colb = lane & 15;
#pragma unroll
    for (int ct = 0; ct < 4; ++ct)
#pragma unroll
        for (int r = 0; r < 4; ++r)
            h[(size_t)(orow + r) * FOUT + ct * 16 + colb] = acc[ct][r];
}

// ---------------------------------------------------------------------------
// Per-dst-node gather-aggregate + norm + bias + PReLU. One wave per node,
// lane = feature. XCD-swizzled blockIdx for L2 locality of h.
// ---------------------------------------------------------------------------
__global__ __launch_bounds__(256) void agg_kernel(const float* __restrict__ h,
                                                  const int* __restrict__ offs,
                                                  const int* __restrict__ deg_in,
                                                  const int* __restrict__ ssrc,
                                                  const float* __restrict__ bias,
                                                  const float* __restrict__ prelu,
                                                  float* __restrict__ hf) {
    int nb = gridDim.x;                       // 32768 (multiple of 8)
    int bid = blockIdx.x;
    int sw = (bid & 7) * (nb >> 3) + (bid >> 3);
    int node = sw * 4 + (threadIdx.x >> 6);
    int lane = threadIdx.x & 63;
    int off = offs[node];
    int d = deg_in[node];
    float acc = 0.f;
    for (int i = 0; i < d; ++i) {
        int s = ssrc[off + i];
        acc += h[(size_t)s * FOUT + lane];
    }
    float v = acc * rsqrtf((float)max(d, 1)) + bias[lane];
    float a = prelu[0];
    hf[(size_t)node * FOUT + lane] = (v > 0.f) ? v : a * v;
}

// ---------------------------------------------------------------------------
// Ragged mean-pool over first 127 nodes + anchor extraction. 1 block/subgraph.
// ---------------------------------------------------------------------------
__global__ __launch_bounds__(256) void pool_kernel(const float* __restrict__ hf,
                                                   float* __restrict__ out) {
    int g = blockIdx.x;
    int col = threadIdx.x & 63;
    int q = threadIdx.x >> 6;
    float acc = 0.f;
    for (int r = q; r < SSUB - 1; r += 4)
        acc += hf[((size_t)g * SSUB + r) * FOUT + col];
    __shared__ float sb[4][64];
    sb[q][col] = acc;
    __syncthreads();
    if (q == 0) {
        float s = (sb[0][col] + sb[1][col]) + (sb[2][col] + sb[3][col]);
        out[(size_t)g * FOUT + col] = s * (1.0f / 127.0f);
        out[(size_t)(BSUB + g) * FOUT + col] = hf[((size_t)g * SSUB + (SSUB - 1)) * FOUT + col];
    }
}

// ---------------------------------------------------------------------------
extern "C" void kernel_launch(void* const* d_in, const int* in_sizes, int n_in,
                              void* d_out, int out_size, void* d_ws, size_t ws_size,
                              hipStream_t stream) {
    const float* in_feat = (const float*)d_in[0];
    const float* W       = (const float*)d_in[1];
    const float* bias    = (const float*)d_in[2];
    const float* prelu   = (const float*)d_in[3];
    const int*   src     = (const int*)d_in[4];
    const int*   dst     = (const int*)d_in[5];
    float* out = (float*)d_out;

    char* ws = (char*)d_ws;
    int*   deg_out = (int*)(ws);                          // N ints   (512 KB)
    int*   deg_in  = (int*)(ws + 524288);                 // N ints
    int*   offs    = (int*)(ws + 1048576);                // N ints
    int*   cursor  = (int*)(ws + 1572864);                // N ints
    int*   gcount  = (int*)(ws + 2097152);                // 1 int (256 B pad)
    short* wfrag   = (short*)(ws + 2097408);              // 40960 B
    float* h       = (float*)(ws + 4194304);              // N*64 f32 (32 MB)
    float* hf      = (float*)(ws + 4194304 + 33554432);   // N*64 f32 (32 MB)
    int*   ssrc    = (int*)(ws + 4194304 + 67108864);     // E ints (8 MB)

    // zero deg_out/deg_in/offs/cursor/gcount
    hipMemsetAsync(ws, 0, 2097408, stream);

    hipLaunchKernelGGL(prep_w_kernel,   dim3(10),           dim3(256), 0, stream, W, wfrag);
    hipLaunchKernelGGL(count_deg_kernel,dim3(NEDGES / 256), dim3(256), 0, stream, src, dst, deg_out, deg_in);
    hipLaunchKernelGGL(assign_off_kernel,dim3(NNODES / 256),dim3(256), 0, stream, deg_in, offs, cursor, gcount);
    hipLaunchKernelGGL(bucket_kernel,   dim3(NEDGES / 256), dim3(256), 0, stream, src, dst, cursor, ssrc);
    hipLaunchKernelGGL(gemm_kernel,     dim3(NNODES / 64),  dim3(256), 0, stream, in_feat, deg_out, wfrag, h);
    hipLaunchKernelGGL(agg_kernel,      dim3(NNODES / 4),   dim3(256), 0, stream, h, offs, deg_in, ssrc, bias, prelu, hf);
    hipLaunchKernelGGL(pool_kernel,     dim3(BSUB),         dim3(256), 0, stream, hf, out);
}